// Round 7
// baseline (373.473 us; speedup 1.0000x reference)
//
#include <hip/hip_runtime.h>
#include <hip/hip_bf16.h>

#define S 4096
#define D 256
#define NB 4

typedef __attribute__((ext_vector_type(8))) __bf16 bf16x8;
typedef __attribute__((ext_vector_type(8))) short s16x8;
typedef __attribute__((ext_vector_type(4))) short s16x4;
typedef __attribute__((ext_vector_type(4))) float f32x4;
typedef __attribute__((ext_vector_type(8))) _Float16 h16x8;

#define MFMA(a, b, c) __builtin_amdgcn_mfma_f32_16x16x32_bf16(a, b, c, 0, 0, 0)
#define MFMA8(a, b, c) __builtin_amdgcn_mfma_f32_16x16x32_fp8_fp8(a, b, c, 0, 0, 0)

__device__ __forceinline__ short f2bf(float f) {
    union { float f; unsigned u; } v; v.f = f;
    unsigned r = v.u + 0x7fffu + ((v.u >> 16) & 1u);   // RNE
    return (short)(r >> 16);
}

// native cast -> v_cvt_pk_bf16_f32 on gfx950 (RNE)
__device__ __forceinline__ short f2bf_hw(float f) {
    __bf16 h = (__bf16)f;
    return __builtin_bit_cast(short, h);
}

__device__ __forceinline__ void g2lds16(const char* g, char* l) {
    __builtin_amdgcn_global_load_lds(
        (const __attribute__((address_space(1))) unsigned int*)g,
        (__attribute__((address_space(3))) unsigned int*)l, 16, 0, 0);
}

// ---------------- prep: x -> fp8(XOR-swizzled) + bf16 x^T (PV-permuted) + norms; W -> bf16 ----
// x^T is stored with an intra-32 K-permutation matching the in-register P layout of k_attn:
// within each 32-t chunk, position p = a*8+j holds logical t = a*4+j (j<4) / 16+a*4+(j-4).
__global__ __launch_bounds__(256) void k_prep(const float* __restrict__ x,
                                              const float* __restrict__ Wv,
                                              unsigned char* __restrict__ xb8,
                                              short* __restrict__ xt,
                                              short* __restrict__ wb,
                                              float* __restrict__ sqg) {
    const int tid = threadIdx.x;
    if (blockIdx.x >= 512) {   // W fp32 -> bf16
        int idx = (((int)blockIdx.x - 512) * 256 + tid) * 16;
        #pragma unroll
        for (int h = 0; h < 2; h++) {
            float4 f0 = *(const float4*)(Wv + idx + h * 8);
            float4 f1 = *(const float4*)(Wv + idx + h * 8 + 4);
            s16x8 o;
            o[0] = f2bf(f0.x); o[1] = f2bf(f0.y); o[2] = f2bf(f0.z); o[3] = f2bf(f0.w);
            o[4] = f2bf(f1.x); o[5] = f2bf(f1.y); o[6] = f2bf(f1.z); o[7] = f2bf(f1.w);
            *(s16x8*)(wb + idx + h * 8) = o;
        }
        return;
    }

    __shared__ short sX[32 * 264];
    const int b = blockIdx.x >> 7, s0 = (blockIdx.x & 127) * 32;
    const int row = tid >> 3, c8 = tid & 7;
    {
        const float* src = x + (size_t)(b * S + s0 + row) * D + c8 * 32;
        unsigned char* xrow = xb8 + (size_t)(b * S + s0 + row) * D;
        float ss = 0.f;
        int p8[8];
        #pragma unroll
        for (int j = 0; j < 8; j++) {
            float4 v = ((const float4*)src)[j];
            ss += v.x * v.x + v.y * v.y + v.z * v.z + v.w * v.w;
            s16x4 o;
            o.x = f2bf(v.x); o.y = f2bf(v.y); o.z = f2bf(v.z); o.w = f2bf(v.w);
            *(s16x4*)(sX + row * 264 + c8 * 32 + j * 4) = o;
            int pk = __builtin_amdgcn_cvt_pk_fp8_f32(v.x, v.y, 0, false);
            p8[j] = __builtin_amdgcn_cvt_pk_fp8_f32(v.z, v.w, pk, true);
        }
        ss += __shfl_xor(ss, 1, 64);
        ss += __shfl_xor(ss, 2, 64);
        ss += __shfl_xor(ss, 4, 64);
        int4 lo = {p8[0], p8[1], p8[2], p8[3]};
        int4 hi = {p8[4], p8[5], p8[6], p8[7]};
        *(int4*)(xrow + (((2 * c8) ^ (row & 7)) << 4)) = lo;
        *(int4*)(xrow + (((2 * c8 + 1) ^ (row & 7)) << 4)) = hi;
        if (c8 == 0) sqg[b * S + s0 + row] = ss;
    }
    __syncthreads();
    {   // transposed + K-permuted write: thread owns d = tid, gathers 32 s-values
        short tmp[32];
        #pragma unroll
        for (int s = 0; s < 32; s++) tmp[s] = sX[s * 264 + tid];
        short* dst = xt + (size_t)(b * D + tid) * S + s0;
        #pragma unroll
        for (int a = 0; a < 4; a++) {
            s16x8 o;
            #pragma unroll
            for (int j = 0; j < 4; j++) {
                o[j]     = tmp[a * 4 + j];        // t = a*4+j
                o[j + 4] = tmp[16 + a * 4 + j];   // t = 16+a*4+j
            }
            *(s16x8*)(dst + a * 8) = o;
        }
    }
}

// ---------------- Main fused attention (R7: P stays in registers, no sK) ----------------
// 256 threads = 4 waves. Wave w owns q-group [q0+w*16, +16) END TO END:
//   Gram (swapped): A = t-tile rows (LDS), B = xq -> lane holds P[q=col][8 t's].
//   Cauchy -> af (bf16x8) IN REGISTERS; K-order of PV matches via permuted x^T layout.
//   PV: acc[16] = full 256-d row block; A = af (own), B = vb from permuted x^T.
// Only LDS: sXt double-buffered t-tile staging (global_load_lds), 1 barrier/iter.
template <int TSPLIT>
__global__ __launch_bounds__(256) void k_attn(const unsigned char* __restrict__ xb8,
                                              const short* __restrict__ xt,
                                              const float* __restrict__ sq,
                                              const float* __restrict__ logt,
                                              _Float16* __restrict__ pex,
                                              float* __restrict__ rws) {
    __shared__ char sXt[2][32 * 256];   // 16384 B (only LDS)

    const int tid = threadIdx.x;
    const int w = tid >> 6, lane = tid & 63;
    const int col = lane & 15, quad = lane >> 4;
    const int cx = col & 7;

    constexpr int LT = (TSPLIT == 4) ? 2 : 1;
    const int th = blockIdx.x & (TSPLIT - 1);
    const int b  = (blockIdx.x >> LT) & 3;
    const int qt = blockIdx.x >> (LT + 2);
    const int q0 = qt * 64;
    const int t_base = th * (S / TSPLIT);
    const int NT = (S / TSPLIT) / 32;

    float temp = fmaxf(__expf(logt[0]), 1e-5f);
    float t2 = temp * temp;
    float t2inv = __builtin_amdgcn_rcpf(t2);

    const unsigned char* xtb = xb8 + (size_t)b * S * D;
    const short* vtb = xt + (size_t)b * D * S;
    const float* sqb = sq + b * S;

    // swizzled fp8 k-chunk offsets (loop-invariant)
    int ofs[8];
    #pragma unroll
    for (int ks = 0; ks < 8; ks++)
        ofs[ks] = (((ks * 2 + (quad >> 1)) ^ cx) << 4) + (quad & 1) * 8;

    const int gq = q0 + w * 16 + col;    // this lane's q (Gram/Cauchy ownership)
    long xq[8];
    {
        const unsigned char* xrow = xtb + (size_t)gq * D;
        #pragma unroll
        for (int ks = 0; ks < 8; ks++)
            xq[ks] = *(const long*)(xrow + ofs[ks]);
    }
    const float stq = sqb[gq] + t2;      // t2 + ||x_q||^2

    f32x4 acc[16];                       // wave's 16 q-rows x 256 d (64 AGPR)
    #pragma unroll
    for (int ni = 0; ni < 16; ni++)
        acc[ni] = (f32x4){0.f, 0.f, 0.f, 0.f};
    float rs = 0.f;
    bf16x8 afp = {};                     // P fragment of previous tile (in-register)

    // V row base for this lane: row (ni*16+col), element offset quad*8 (permuted layout)
    const short* vbase = vtb + (size_t)col * S + quad * 8;

    {   // prologue: async-stage tile 0
        const char* g = (const char*)(xtb + (size_t)t_base * D);
        #pragma unroll
        for (int p = 0; p < 2; p++) {
            int c = p * 256 + tid;
            g2lds16(g + c * 16, &sXt[0][c * 16]);
        }
    }

    for (int i = 0; i < NT; i++) {
        const int t0 = t_base + i * 32;
        const int cur = i & 1;
        __syncthreads();   // sXt[cur] staged (issued a full iteration ago)

        if (i + 1 < NT) {   // stage next tile
            const char* g = (const char*)(xtb + (size_t)(t0 + 32) * D);
            #pragma unroll
            for (int p = 0; p < 2; p++) {
                int c = p * 256 + tid;
                g2lds16(g + c * 16, &sXt[cur ^ 1][c * 16]);
            }
        }

        // Gram(i), swapped: A = t-rows from LDS, B = xq. 4 independent chains.
        f32x4 pa0 = (f32x4){0.f,0.f,0.f,0.f}, pa1 = (f32x4){0.f,0.f,0.f,0.f};
        f32x4 pb0 = (f32x4){0.f,0.f,0.f,0.f}, pb1 = (f32x4){0.f,0.f,0.f,0.f};
        {
            const char* r0 = &sXt[cur][col * 256];
            const char* r1 = &sXt[cur][(col + 16) * 256];
            #pragma unroll
            for (int ks = 0; ks < 4; ks++) {
                long a0 = *(const long*)(r0 + ofs[ks]);
                long a1 = *(const long*)(r1 + ofs[ks]);
                long a2 = *(const long*)(r0 + ofs[ks + 4]);
                long a3 = *(const long*)(r1 + ofs[ks + 4]);
                pa0 = MFMA8(a0, xq[ks], pa0);       // t 0-15
                pa1 = MFMA8(a1, xq[ks], pa1);       // t 16-31
                pb0 = MFMA8(a2, xq[ks + 4], pb0);   // t 0-15
                pb1 = MFMA8(a3, xq[ks + 4], pb1);   // t 16-31
            }
        }

        // PV(i-1): A = afp (register), B = vb from permuted x^T. Independent of Gram.
        if (i > 0) {
            const int tp = t0 - 32;
            __builtin_amdgcn_s_setprio(1);
            #pragma unroll
            for (int ni = 0; ni < 16; ni++) {
                bf16x8 vb = *(const bf16x8*)(vbase + (size_t)ni * 16 * S + tp);
                acc[ni] = MFMA(afp, vb, acc[ni]);
            }
            __builtin_amdgcn_s_setprio(0);
        }

        // Cauchy(i): u = 1/max(t2 + d2raw, t2); lane owns q=gq, 8 t's. Result -> afp.
        {
            f32x4 sqt0 = *(const f32x4*)(sqb + t0 + quad * 4);
            f32x4 sqt1 = *(const f32x4*)(sqb + t0 + 16 + quad * 4);
            f32x4 p2v0 = pa0 + pb0;   // t = quad*4 + rr
            f32x4 p2v1 = pa1 + pb1;   // t = 16 + quad*4 + rr
            const bool dg = ((unsigned)(t0 - q0) < 64u);
            const int qmt = gq - t0;
            s16x8 o;
            if (dg) {
                #pragma unroll
                for (int rr = 0; rr < 4; rr++) {
                    float d0 = fmaxf(stq + sqt0[rr] - 2.f * p2v0[rr], t2);
                    float u0 = __builtin_amdgcn_rcpf(d0);
                    if (qmt == quad * 4 + rr) u0 = t2inv;
                    float d1 = fmaxf(stq + sqt1[rr] - 2.f * p2v1[rr], t2);
                    float u1 = __builtin_amdgcn_rcpf(d1);
                    if (qmt == 16 + quad * 4 + rr) u1 = t2inv;
                    rs += u0 + u1;
                    o[rr]     = f2bf_hw(u0);
                    o[rr + 4] = f2bf_hw(u1);
                }
            } else {
                #pragma unroll
                for (int rr = 0; rr < 4; rr++) {
                    float d0 = fmaxf(stq + sqt0[rr] - 2.f * p2v0[rr], t2);
                    float u0 = __builtin_amdgcn_rcpf(d0);
                    float d1 = fmaxf(stq + sqt1[rr] - 2.f * p2v1[rr], t2);
                    float u1 = __builtin_amdgcn_rcpf(d1);
                    rs += u0 + u1;
                    o[rr]     = f2bf_hw(u0);
                    o[rr + 4] = f2bf_hw(u1);
                }
            }
            afp = __builtin_bit_cast(bf16x8, o);
        }
    }

    {   // epilogue: PV(NT-1)
        const int tp = t_base + (NT - 1) * 32;
        #pragma unroll
        for (int ni = 0; ni < 16; ni++) {
            bf16x8 vb = *(const bf16x8*)(vbase + (size_t)ni * 16 * S + tp);
            acc[ni] = MFMA(afp, vb, acc[ni]);
        }
    }

    // rowsum: quads partition the t's of q=gq -> reduce across quads, write from quad 0.
    rs += __shfl_xor(rs, 16, 64);
    rs += __shfl_xor(rs, 32, 64);
    if (quad == 0) rws[(size_t)th * NB * S + b * S + gq] = rs;

    // store: C row = q0 + w*16 + quad*4 + rr, col = ni*16 + col
    _Float16* ob = pex + (size_t)th * NB * S * D + (size_t)(b * S + q0 + w * 16) * D;
    #pragma unroll
    for (int ni = 0; ni < 16; ni++)
        #pragma unroll
        for (int rr = 0; rr < 4; rr++)
            ob[(size_t)(quad * 4 + rr) * D + ni * 16 + col] = (_Float16)acc[ni][rr];
}

// ---------------- post: out = (sum(Yp)/sum(rp)) @ W^T + b ----------------
template <int NP>
__global__ __launch_bounds__(256) void k_post(const _Float16* __restrict__ pex,
                                              const float* __restrict__ rws,
                                              const short* __restrict__ wb,
                                              const float* __restrict__ bv,
                                              float* __restrict__ out) {
    __shared__ short sY[32 * 264];

    const int tid = threadIdx.x;
    const int w = tid >> 6, lane = tid & 63;
    const int col = lane & 15, quad = lane >> 4;
    const int b = blockIdx.x >> 7, s0 = (blockIdx.x & 127) * 32;

    // W preload (bf16): wf[4][8]
    bf16x8 wf[4][8];
    #pragma unroll
    for (int ni = 0; ni < 4; ni++)
        #pragma unroll
        for (int ks = 0; ks < 8; ks++)
            wf[ni][ks] = *(const bf16x8*)(wb + (size_t)(w * 64 + ni * 16 + col) * D + ks * 32 + quad * 8);

    {   // load partials, normalize, stage bf16
        const int row = tid >> 3, c8 = tid & 7;
        const int gs = b * S + s0 + row;
        float rsum = rws[gs];
        #pragma unroll
        for (int p = 1; p < NP; p++) rsum += rws[(size_t)p * NB * S + gs];
        float rinv = __builtin_amdgcn_rcpf(fmaxf(rsum, 1e-8f));
        const _Float16* y0 = pex + (size_t)gs * D + c8 * 32;
        #pragma unroll
        for (int j = 0; j < 4; j++) {
            float f[8] = {0.f, 0.f, 0.f, 0.f, 0.f, 0.f, 0.f, 0.f};
            #pragma unroll
            for (int p = 0; p < NP; p++) {
                h16x8 a = *(const h16x8*)(y0 + (size_t)p * NB * S * D + j * 8);
                #pragma unroll
                for (int e = 0; e < 8; e++) f[e] += (float)a[e];
            }
            s16x8 o;
            #pragma unroll
            for (int e = 0; e < 8; e++) o[e] = f2bf_hw(f[e] * rinv);
            *(s16x8*)(sY + row * 264 + c8 * 32 + j * 8) = o;
        }
    }
    __syncthreads();

    f32x4 acc[2][4];
    #pragma unroll
    for (int mi = 0; mi < 2; mi++)
        #pragma unroll
        for (int ni = 0; ni < 4; ni++)
            acc[mi][ni] = (f32x4){0.f, 0.f, 0.f, 0.f};

    #pragma unroll
    for (int ks = 0; ks < 8; ks++) {
        bf16x8 a[2];
        #pragma unroll
        for (int mi = 0; mi < 2; mi++)
            a[mi] = *(const bf16x8*)(sY + (mi * 16 + col) * 264 + ks * 32 + quad * 8);
        #pragma unroll
        for (int mi = 0; mi < 2; mi++)
            #pragma unroll
            for (int ni = 0; ni < 4; ni++)
                acc[mi][ni] = MFMA(a[mi], wf[ni][ks], acc[mi][ni]);
    }

    float* ob = out + (size_t)(b * S + s0) * D;
    #pragma unroll
    for (int ni = 0; ni < 4; ni++) {
        int d = w * 64 + ni * 16 + col;
        float bvv = bv[d];
        #pragma unroll
        for (int mi = 0; mi < 2; mi++)
            #pragma unroll
            for (int r = 0; r < 4; r++)
                ob[(size_t)(mi * 16 + quad * 4 + r) * D + d] = acc[mi][ni][r] + bvv;
    }
}

extern "C" void kernel_launch(void* const* d_in, const int* in_sizes, int n_in,
                              void* d_out, int out_size, void* d_ws, size_t ws_size,
                              hipStream_t stream) {
    const float* x    = (const float*)d_in[0];
    const float* Wv   = (const float*)d_in[1];
    const float* bv   = (const float*)d_in[2];
    const float* logt = (const float*)d_in[3];
    float* out = (float*)d_out;

    char* ws = (char*)d_ws;
    unsigned char* xb8 = (unsigned char*)ws;          // fp8 x (swizzled) [B][S][D]   4 MB
    short* xt  = (short*)(ws + 4194304);              // bf16 x^T (PV-permuted)       8 MB
    short* wb  = (short*)(ws + 12582912);             // bf16 W [D][D]                128 KB
    float* sq  = (float*)(ws + 12713984);             // ||x||^2 [B][S]               64 KB
    float* rws = (float*)(ws + 12779520);             // rowsums [2][B][S]            128 KB
    _Float16* pex = (_Float16*)(ws + 13041664);       // fp16 Y partials [2][B][S][D] 16.78 MB

    k_prep<<<528, 256, 0, stream>>>(x, Wv, xb8, xt, wb, sq);
    k_attn<2><<<NB * (S / 64) * 2, 256, 0, stream>>>(xb8, xt, sq, logt, pex, rws);
    k_post<2><<<NB * (S / 32), 256, 0, stream>>>(pex, rws, wb, bv, out);
}

// Round 9
// 185.904 us; speedup vs baseline: 2.0090x; 2.0090x over previous
//
#include <hip/hip_runtime.h>
#include <hip/hip_bf16.h>

#define S 4096
#define D 256
#define NB 4

typedef __attribute__((ext_vector_type(8))) __bf16 bf16x8;
typedef __attribute__((ext_vector_type(8))) short s16x8;
typedef __attribute__((ext_vector_type(4))) short s16x4;
typedef __attribute__((ext_vector_type(4))) float f32x4;
typedef __attribute__((ext_vector_type(8))) _Float16 h16x8;

#define MFMA(a, b, c) __builtin_amdgcn_mfma_f32_16x16x32_bf16(a, b, c, 0, 0, 0)
#define MFMA8(a, b, c) __builtin_amdgcn_mfma_f32_16x16x32_fp8_fp8(a, b, c, 0, 0, 0)

__device__ __forceinline__ short f2bf(float f) {
    union { float f; unsigned u; } v; v.f = f;
    unsigned r = v.u + 0x7fffu + ((v.u >> 16) & 1u);   // RNE
    return (short)(r >> 16);
}

// native cast -> v_cvt_pk_bf16_f32 on gfx950 (RNE)
__device__ __forceinline__ short f2bf_hw(float f) {
    __bf16 h = (__bf16)f;
    return __builtin_bit_cast(short, h);
}

__device__ __forceinline__ void g2lds16(const char* g, char* l) {
    __builtin_amdgcn_global_load_lds(
        (const __attribute__((address_space(1))) unsigned int*)g,
        (__attribute__((address_space(3))) unsigned int*)l, 16, 0, 0);
}

// ---------------- prep (slim): x -> fp8(XOR-swizzled) + row norms; W -> bf16 ----------------
// No x^T transpose anymore (PV consumes v = x@W^T, built by k_vw). No LDS, no barrier.
__global__ __launch_bounds__(256) void k_prep(const float* __restrict__ x,
                                              const float* __restrict__ Wv,
                                              unsigned char* __restrict__ xb8,
                                              short* __restrict__ wb,
                                              float* __restrict__ sqg) {
    const int tid = threadIdx.x;
    if (blockIdx.x >= 512) {   // W fp32 -> bf16
        int idx = (((int)blockIdx.x - 512) * 256 + tid) * 16;
        #pragma unroll
        for (int h = 0; h < 2; h++) {
            float4 f0 = *(const float4*)(Wv + idx + h * 8);
            float4 f1 = *(const float4*)(Wv + idx + h * 8 + 4);
            s16x8 o;
            o[0] = f2bf(f0.x); o[1] = f2bf(f0.y); o[2] = f2bf(f0.z); o[3] = f2bf(f0.w);
            o[4] = f2bf(f1.x); o[5] = f2bf(f1.y); o[6] = f2bf(f1.z); o[7] = f2bf(f1.w);
            *(s16x8*)(wb + idx + h * 8) = o;
        }
        return;
    }

    const int b = blockIdx.x >> 7, s0 = (blockIdx.x & 127) * 32;
    const int row = tid >> 3, c8 = tid & 7;
    const float* src = x + (size_t)(b * S + s0 + row) * D + c8 * 32;
    unsigned char* xrow = xb8 + (size_t)(b * S + s0 + row) * D;
    float ss = 0.f;
    int p8[8];
    #pragma unroll
    for (int j = 0; j < 8; j++) {
        float4 v = ((const float4*)src)[j];
        ss += v.x * v.x + v.y * v.y + v.z * v.z + v.w * v.w;
        int pk = __builtin_amdgcn_cvt_pk_fp8_f32(v.x, v.y, 0, false);
        p8[j] = __builtin_amdgcn_cvt_pk_fp8_f32(v.z, v.w, pk, true);
    }
    ss += __shfl_xor(ss, 1, 64);
    ss += __shfl_xor(ss, 2, 64);
    ss += __shfl_xor(ss, 4, 64);
    int4 lo = {p8[0], p8[1], p8[2], p8[3]};
    int4 hi = {p8[4], p8[5], p8[6], p8[7]};
    *(int4*)(xrow + (((2 * c8) ^ (row & 7)) << 4)) = lo;
    *(int4*)(xrow + (((2 * c8 + 1) ^ (row & 7)) << 4)) = hi;
    if (c8 == 0) sqg[b * S + s0 + row] = ss;
}

// ---------------- vw: v^T = (x @ W^T)^T, bf16 [B][D][S] ----------------
// Welds k_post's verified 32x256 GEMM fragment logic with k_prep's verified
// LDS transpose-write. Replaces the old x^T transpose (same output traffic).
__global__ __launch_bounds__(256) void k_vw(const float* __restrict__ x,
                                            const short* __restrict__ wb,
                                            short* __restrict__ vt) {
    __shared__ short sX[32 * 264];

    const int tid = threadIdx.x;
    const int w = tid >> 6, lane = tid & 63;
    const int col = lane & 15, quad = lane >> 4;
    const int b = blockIdx.x >> 7, s0 = (blockIdx.x & 127) * 32;

    // W preload (global, L2-hot): independent of the LDS staging below
    bf16x8 wf[4][8];
    #pragma unroll
    for (int ni = 0; ni < 4; ni++)
        #pragma unroll
        for (int ks = 0; ks < 8; ks++)
            wf[ni][ks] = *(const bf16x8*)(wb + (size_t)(w * 64 + ni * 16 + col) * D + ks * 32 + quad * 8);

    {   // stage x tile as bf16 [32][264]
        const int row = tid >> 3, c8 = tid & 7;
        const float* src = x + (size_t)(b * S + s0 + row) * D + c8 * 32;
        #pragma unroll
        for (int j = 0; j < 8; j++) {
            float4 v = ((const float4*)src)[j];
            s16x4 o;
            o.x = f2bf(v.x); o.y = f2bf(v.y); o.z = f2bf(v.z); o.w = f2bf(v.w);
            *(s16x4*)(sX + row * 264 + c8 * 32 + j * 4) = o;
        }
    }
    __syncthreads();

    f32x4 acc[2][4];
    #pragma unroll
    for (int mi = 0; mi < 2; mi++)
        #pragma unroll
        for (int ni = 0; ni < 4; ni++)
            acc[mi][ni] = (f32x4){0.f, 0.f, 0.f, 0.f};

    #pragma unroll
    for (int ks = 0; ks < 8; ks++) {
        bf16x8 a[2];
        #pragma unroll
        for (int mi = 0; mi < 2; mi++)
            a[mi] = *(const bf16x8*)(sX + (mi * 16 + col) * 264 + ks * 32 + quad * 8);
        #pragma unroll
        for (int mi = 0; mi < 2; mi++)
            #pragma unroll
            for (int ni = 0; ni < 4; ni++)
                acc[mi][ni] = MFMA(a[mi], wf[ni][ks], acc[mi][ni]);
    }

    __syncthreads();   // all sX reads done -> safe to overwrite with v
    // v tile back into LDS in [s][d] layout (C layout verified in k_post)
    #pragma unroll
    for (int mi = 0; mi < 2; mi++)
        #pragma unroll
        for (int ni = 0; ni < 4; ni++)
            #pragma unroll
            for (int r = 0; r < 4; r++)
                sX[(mi * 16 + quad * 4 + r) * 264 + w * 64 + ni * 16 + col] =
                    f2bf_hw(acc[mi][ni][r]);
    __syncthreads();

    {   // transposed write: thread owns d = tid, gathers 32 s-values (prep's pattern)
        short tmp[32];
        #pragma unroll
        for (int s = 0; s < 32; s++) tmp[s] = sX[s * 264 + tid];
        short* dst = vt + (size_t)(b * D + tid) * S + s0;
        #pragma unroll
        for (int i = 0; i < 4; i++)
            *(s16x8*)(dst + i * 8) = *(const s16x8*)(tmp + i * 8);
    }
}

// ---------------- Main fused attention (R0 structure, UNCHANGED; V = vt) ----------------
// 256 threads = 4 waves. q-tile 64, t-tile 32. Gram fp8 (A=regs, B=LDS), PV bf16 vs v^T.
// Writes UNNORMALIZED Y = K@v (fp16) + rowsums; k_post normalizes and adds bias.
template <int TSPLIT>
__global__ __launch_bounds__(256) void k_attn(const unsigned char* __restrict__ xb8,
                                              const short* __restrict__ vt,
                                              const float* __restrict__ sq,
                                              const float* __restrict__ logt,
                                              _Float16* __restrict__ pex,
                                              float* __restrict__ rws) {
    __shared__ char sXt[2][32 * 256];
    __shared__ short sK[2][64 * 36];
    __shared__ float sRow[64];

    const int tid = threadIdx.x;
    const int w = tid >> 6, lane = tid & 63;
    const int col = lane & 15, quad = lane >> 4;
    const int cx = col & 7;

    const int b  = (blockIdx.x & 7) >> 1;
    const int th = blockIdx.x & 1;
    const int qt = blockIdx.x >> 3;
    const int q0 = qt * 64;
    const int t_base = th * (S / TSPLIT);
    const int NT = (S / TSPLIT) / 32;

    float temp = fmaxf(__expf(logt[0]), 1e-5f);
    float t2 = temp * temp;
    float t2inv = __builtin_amdgcn_rcpf(t2);

    const unsigned char* xtb = xb8 + (size_t)b * S * D;
    const short* vtb = vt + (size_t)b * D * S;
    const float* sqb = sq + b * S;

    long xq[8];
    {
        const unsigned char* xrow = xtb + (size_t)(q0 + w * 16 + col) * D;
        #pragma unroll
        for (int ks = 0; ks < 8; ks++)
            xq[ks] = *(const long*)(xrow + (((ks * 2 + (quad >> 1)) ^ cx) << 4) + (quad & 1) * 8);
    }
    float sqq[4];
    #pragma unroll
    for (int rr = 0; rr < 4; rr++)
        sqq[rr] = sqb[q0 + w * 16 + quad * 4 + rr];

    f32x4 acc[4][4];
    #pragma unroll
    for (int mi = 0; mi < 4; mi++)
        #pragma unroll
        for (int ni = 0; ni < 4; ni++)
            acc[mi][ni] = (f32x4){0.f, 0.f, 0.f, 0.f};
    float rs[4] = {0.f, 0.f, 0.f, 0.f};

    {   // prologue: async-stage tile 0
        const char* g = (const char*)(xtb + (size_t)t_base * D);
        #pragma unroll
        for (int p = 0; p < 2; p++) {
            int c = p * 256 + tid;
            g2lds16(g + c * 16, &sXt[0][c * 16]);
        }
    }

    for (int i = 0; i < NT; i++) {
        const int t0 = t_base + i * 32;
        const int cur = i & 1;
        __syncthreads();

        if (i + 1 < NT) {
            const char* g = (const char*)(xtb + (size_t)(t0 + 32) * D);
            #pragma unroll
            for (int p = 0; p < 2; p++) {
                int c = p * 256 + tid;
                g2lds16(g + c * 16, &sXt[cur ^ 1][c * 16]);
            }
        }

        bf16x8 vb[4];
        if (i > 0) {
            const int tp = t0 - 32;
            #pragma unroll
            for (int ni = 0; ni < 4; ni++)
                vb[ni] = *(const bf16x8*)(vtb + (size_t)(w * 64 + ni * 16 + col) * S + tp + quad * 8);
        }
        float sqt0 = sqb[t0 + col], sqt1 = sqb[t0 + 16 + col];

        f32x4 p2v[2];
        p2v[0] = (f32x4){0.f, 0.f, 0.f, 0.f};
        p2v[1] = (f32x4){0.f, 0.f, 0.f, 0.f};
        #pragma unroll
        for (int ks = 0; ks < 8; ks++) {
            int co = (((ks * 2 + (quad >> 1)) ^ cx) << 4) + (quad & 1) * 8;
            long b0 = *(const long*)(&sXt[cur][col * 256 + co]);
            long b1 = *(const long*)(&sXt[cur][(col + 16) * 256 + co]);
            p2v[0] = MFMA8(xq[ks], b0, p2v[0]);
            p2v[1] = MFMA8(xq[ks], b1, p2v[1]);
        }

        #pragma unroll
        for (int t_ = 0; t_ < 2; t_++) {
            float sqt = t_ ? sqt1 : sqt0;
            int tg = t0 + t_ * 16 + col;
            #pragma unroll
            for (int rr = 0; rr < 4; rr++) {
                float d2 = fmaxf(sqq[rr] + sqt - 2.f * p2v[t_][rr], 0.f);
                float u = __builtin_amdgcn_rcpf(t2 + d2);   // normalization cancels t2
                if (q0 + w * 16 + quad * 4 + rr == tg) u = t2inv;   // exact diagonal (kv=1)
                rs[rr] += u;
                sK[cur][(w * 16 + quad * 4 + rr) * 36 + t_ * 16 + col] = f2bf(u);
            }
        }

        if (i > 0) {
            #pragma unroll
            for (int mi = 0; mi < 4; mi++) {
                bf16x8 af = *(const bf16x8*)(&sK[cur ^ 1][(mi * 16 + col) * 36 + quad * 8]);
                #pragma unroll
                for (int ni = 0; ni < 4; ni++)
                    acc[mi][ni] = MFMA(af, vb[ni], acc[mi][ni]);
            }
        }
    }

    __syncthreads();
    {   // final PV
        const int tp = t_base + (NT - 1) * 32;
        const int cur = (NT - 1) & 1;
        bf16x8 vb[4];
        #pragma unroll
        for (int ni = 0; ni < 4; ni++)
            vb[ni] = *(const bf16x8*)(vtb + (size_t)(w * 64 + ni * 16 + col) * S + tp + quad * 8);
        #pragma unroll
        for (int mi = 0; mi < 4; mi++) {
            bf16x8 af = *(const bf16x8*)(&sK[cur][(mi * 16 + col) * 36 + quad * 8]);
            #pragma unroll
            for (int ni = 0; ni < 4; ni++)
                acc[mi][ni] = MFMA(af, vb[ni], acc[mi][ni]);
        }
    }

    #pragma unroll
    for (int rr = 0; rr < 4; rr++) {
        float v = rs[rr];
        v += __shfl_xor(v, 1, 64);
        v += __shfl_xor(v, 2, 64);
        v += __shfl_xor(v, 4, 64);
        v += __shfl_xor(v, 8, 64);
        if (col == 0) sRow[w * 16 + quad * 4 + rr] = v;
    }
    __syncthreads();

    if (tid < 64) rws[(size_t)th * NB * S + b * S + q0 + tid] = sRow[tid];
    _Float16* ob = pex + (size_t)th * NB * S * D + (size_t)(b * S + q0) * D;
    #pragma unroll
    for (int mi = 0; mi < 4; mi++)
        #pragma unroll
        for (int rr = 0; rr < 4; rr++)
            #pragma unroll
            for (int ni = 0; ni < 4; ni++)
                ob[(size_t)(mi * 16 + quad * 4 + rr) * D + w * 64 + ni * 16 + col] =
                    (_Float16)acc[mi][ni][rr];
}

// ---------------- post (slim): out = (Y0+Y1)/(r0+r1) + b  (pure streaming) ----------------
template <int NP>
__global__ __launch_bounds__(256) void k_post(const _Float16* __restrict__ pex,
                                              const float* __restrict__ rws,
                                              const float* __restrict__ bv,
                                              float* __restrict__ out) {
    const int tid = threadIdx.x;
    const int b = blockIdx.x >> 7, s0 = (blockIdx.x & 127) * 32;
    const int row = tid >> 3, c8 = tid & 7;
    const int gs = b * S + s0 + row;

    float rsum = rws[gs];
    #pragma unroll
    for (int p = 1; p < NP; p++) rsum += rws[(size_t)p * NB * S + gs];
    float rinv = __builtin_amdgcn_rcpf(fmaxf(rsum, 1e-8f));

    const _Float16* y0 = pex + (size_t)gs * D + c8 * 32;
    float* ob = out + (size_t)gs * D + c8 * 32;
    #pragma unroll
    for (int j = 0; j < 4; j++) {
        float f[8] = {0.f, 0.f, 0.f, 0.f, 0.f, 0.f, 0.f, 0.f};
        #pragma unroll
        for (int p = 0; p < NP; p++) {
            h16x8 a = *(const h16x8*)(y0 + (size_t)p * NB * S * D + j * 8);
            #pragma unroll
            for (int e = 0; e < 8; e++) f[e] += (float)a[e];
        }
        f32x4 b0 = *(const f32x4*)(bv + c8 * 32 + j * 8);
        f32x4 b1 = *(const f32x4*)(bv + c8 * 32 + j * 8 + 4);
        f32x4 o0, o1;
        #pragma unroll
        for (int e = 0; e < 4; e++) {
            o0[e] = f[e] * rinv + b0[e];
            o1[e] = f[e + 4] * rinv + b1[e];
        }
        *(f32x4*)(ob + j * 8) = o0;
        *(f32x4*)(ob + j * 8 + 4) = o1;
    }
}

extern "C" void kernel_launch(void* const* d_in, const int* in_sizes, int n_in,
                              void* d_out, int out_size, void* d_ws, size_t ws_size,
                              hipStream_t stream) {
    const float* x    = (const float*)d_in[0];
    const float* Wv   = (const float*)d_in[1];
    const float* bv   = (const float*)d_in[2];
    const float* logt = (const float*)d_in[3];
    float* out = (float*)d_out;

    char* ws = (char*)d_ws;
    unsigned char* xb8 = (unsigned char*)ws;          // fp8 x (swizzled) [B][S][D]   4 MB
    short* vt  = (short*)(ws + 4194304);              // bf16 v^T [B][D][S]           8 MB
    short* wb  = (short*)(ws + 12582912);             // bf16 W [D][D]                128 KB
    float* sq  = (float*)(ws + 12713984);             // ||x||^2 [B][S]               64 KB
    float* rws = (float*)(ws + 12779520);             // rowsums [2][B][S]            128 KB
    _Float16* pex = (_Float16*)(ws + 13041664);       // fp16 Y partials [2][B][S][D] 16.78 MB

    k_prep<<<528, 256, 0, stream>>>(x, Wv, xb8, wb, sq);
    k_vw<<<512, 256, 0, stream>>>(x, wb, vt);
    k_attn<2><<<NB * (S / 64) * 2, 256, 0, stream>>>(xb8, vt, sq, logt, pex, rws);
    k_post<2><<<NB * (S / 32), 256, 0, stream>>>(pex, rws, bv, out);
}